// Round 2
// baseline (304.644 us; speedup 1.0000x reference)
//
#include <hip/hip_runtime.h>

// DynamicFC: out[b,o,h,w] = sum_i w[b,o,i] * x[b,i,h,w] + bias[b,o]
// Batched GEMM per b: M=Cout=512, N=HW=784, K=Cin=512, fp32 in/out.
// R4 vs R3 (R3 post-mortem: VGPR_Count=80 proves the compiler re-sank the
// register prefetch to save regs -> every K-step exposed full L2-miss latency
// at the barrier; MfmaUtil 7.7%, VALUBusy 7.2%, HBM 22% = latency-bound):
//  - __launch_bounds__(256, 2): 256-VGPR budget so prefetch regs stay live.
//  - BK 32 -> 64: 8 iterations, 28 MFMA/wave per step -> compute phase long
//    enough to hide ~600cy load latency under 1-deep register prefetch.
//  - Double-buffered LDS, ONE barrier per K-step:
//      write regs->buf[t&1]; barrier; issue loads(t+1); compute buf[t&1]
//    At the barrier zero vmem is outstanding (prev loads consumed by write),
//    so the compiler's vmcnt(0)-before-s_barrier is free; new loads hide
//    under the whole compute phase. buf written at t+1 was last read at t-1,
//    and all waves passed barrier(t) after that read -> race-free.

#define CIN  512
#define COUT 512
#define HW   784      // 28*28 = 7*112
#define BM   128
#define BN   112
#define BK   64
#define LSTR 72       // 64 + 8 pad bf16 elems (144B row: stride-4 banks, 2-way = free)

typedef __bf16 bf16_t;
typedef __bf16 bf16x8 __attribute__((ext_vector_type(8)));
typedef __bf16 bf16x4 __attribute__((ext_vector_type(4)));
typedef float  f32x4  __attribute__((ext_vector_type(4)));

__device__ __forceinline__ bf16x8 pack8(f32x4 a, f32x4 b) {
    bf16x8 r;
    r[0] = (bf16_t)a[0]; r[1] = (bf16_t)a[1];
    r[2] = (bf16_t)a[2]; r[3] = (bf16_t)a[3];
    r[4] = (bf16_t)b[0]; r[5] = (bf16_t)b[1];
    r[6] = (bf16_t)b[2]; r[7] = (bf16_t)b[3];
    return r;
}

__global__ __launch_bounds__(256, 2) void dynfc_kernel(
    const float* __restrict__ x,     // [64][512][784]
    const float* __restrict__ w,     // [64][512][512]
    const float* __restrict__ bias,  // [64][512]
    float* __restrict__ out)         // [64][512][784]
{
    __shared__ bf16_t Asm[2][BM * LSTR];   // 2 x 18.4 KB
    __shared__ bf16_t Bsm[2][BN * LSTR];   // 2 x 16.1 KB  (total ~69 KB)
    __shared__ float  bias_sm[BM];

    // XCD swizzle: whole batches per XCD so W+X re-reads hit that XCD's L2.
    const int bid   = blockIdx.x;        // 0..1791
    const int xcd   = bid & 7;
    const int j     = bid >> 3;          // 0..223
    const int batch = xcd + 8 * (j / 28);
    const int trem  = j % 28;            // 4 m-tiles * 7 n-tiles
    const int tm    = trem / 7;
    const int tn    = trem % 7;
    const int m0    = tm * BM;
    const int n0    = tn * BN;

    const int tid  = threadIdx.x;
    const int lane = tid & 63;
    const int wid  = tid >> 6;
    const int wm   = wid * 32;           // wave's 32-row slice
    const int l15  = lane & 15;
    const int quad = lane >> 4;

    const float* xb = x + (size_t)batch * CIN * HW;
    const float* wb = w + (size_t)batch * COUT * CIN;

    if (tid < 32) {
        f32x4 bv = *(const f32x4*)(bias + batch * COUT + m0 + tid * 4);
        *(f32x4*)&bias_sm[tid * 4] = bv;
    }

    // A staging: thread -> (row ar, k-half ah of {0,32}); 32 fp32 each
    const int ar = tid >> 1;
    const int ah = (tid & 1) * 32;
    // B staging: thread -> 4 cols x (4+4) k-rows; kg = k-group, ng = n-group
    const int  kg      = tid & 7;
    const int  ng      = tid >> 3;       // 0..31
    const bool bactive = (ng < 28);      // 28*4 = 112 cols exactly

    const float* asrc = wb + (size_t)(m0 + ar) * CIN + ah;
    const float* bsrc = xb + (size_t)(kg * 4) * HW + n0 + ng * 4;

    // ---- prologue: K-tile 0 into registers ----
    f32x4 a[8], b0[4], b1[4];
    #pragma unroll
    for (int u = 0; u < 8; u++) a[u] = *(const f32x4*)(asrc + 4 * u);
    if (bactive) {
        #pragma unroll
        for (int r = 0; r < 4; r++) b0[r] = *(const f32x4*)(bsrc + (size_t)r * HW);
        #pragma unroll
        for (int r = 0; r < 4; r++) b1[r] = *(const f32x4*)(bsrc + (size_t)(32 + r) * HW);
    }

    f32x4 acc[2][7] = {};

    int bufsel = 0;
    for (int t = 0; t < 8; ++t) {
        bf16_t* __restrict__ Ab = &Asm[bufsel][0];
        bf16_t* __restrict__ Bb = &Bsm[bufsel][0];

        // ---- write current tile (regs) -> LDS, converting fp32->bf16 ----
        *(bf16x8*)&Ab[ar * LSTR + ah]      = pack8(a[0], a[1]);
        *(bf16x8*)&Ab[ar * LSTR + ah + 8]  = pack8(a[2], a[3]);
        *(bf16x8*)&Ab[ar * LSTR + ah + 16] = pack8(a[4], a[5]);
        *(bf16x8*)&Ab[ar * LSTR + ah + 24] = pack8(a[6], a[7]);
        if (bactive) {
            #pragma unroll
            for (int nn = 0; nn < 4; nn++) {
                bf16x4 c0, c1;
                c0[0] = (bf16_t)b0[0][nn]; c0[1] = (bf16_t)b0[1][nn];
                c0[2] = (bf16_t)b0[2][nn]; c0[3] = (bf16_t)b0[3][nn];
                c1[0] = (bf16_t)b1[0][nn]; c1[1] = (bf16_t)b1[1][nn];
                c1[2] = (bf16_t)b1[2][nn]; c1[3] = (bf16_t)b1[3][nn];
                *(bf16x4*)&Bb[(ng * 4 + nn) * LSTR + kg * 4]      = c0;
                *(bf16x4*)&Bb[(ng * 4 + nn) * LSTR + 32 + kg * 4] = c1;
            }
        }
        __syncthreads();

        // ---- issue NEXT tile's loads (wrapped at t=7; harmless) ----
        {
            const int kn = ((t + 1) & 7) * BK;
            const float* ap = asrc + kn;
            #pragma unroll
            for (int u = 0; u < 8; u++) a[u] = *(const f32x4*)(ap + 4 * u);
            if (bactive) {
                const float* bp = bsrc + (size_t)kn * HW;
                #pragma unroll
                for (int r = 0; r < 4; r++) b0[r] = *(const f32x4*)(bp + (size_t)r * HW);
                #pragma unroll
                for (int r = 0; r < 4; r++) b1[r] = *(const f32x4*)(bp + (size_t)(32 + r) * HW);
            }
        }

        // ---- compute: 2 k-substeps x (2 m-frags x 7 n-frags) ----
        #pragma unroll
        for (int ks = 0; ks < 2; ks++) {
            const int ko = ks * 32;
            bf16x8 af[2], bfr[7];
            #pragma unroll
            for (int i = 0; i < 2; i++)
                af[i] = *(const bf16x8*)&Ab[(wm + i * 16 + l15) * LSTR + ko + quad * 8];
            #pragma unroll
            for (int j2 = 0; j2 < 7; j2++)
                bfr[j2] = *(const bf16x8*)&Bb[(j2 * 16 + l15) * LSTR + ko + quad * 8];
            #pragma unroll
            for (int i = 0; i < 2; i++)
                #pragma unroll
                for (int j2 = 0; j2 < 7; j2++)
                    acc[i][j2] = __builtin_amdgcn_mfma_f32_16x16x32_bf16(af[i], bfr[j2], acc[i][j2], 0, 0, 0);
        }
        bufsel ^= 1;
    }

    // ---- epilogue: add bias, nontemporal store (7*112 == 784, no guard) ----
    // C/D layout: col = lane&15, row = quad*4 + r
    float* ob = out + (size_t)batch * COUT * HW;
    #pragma unroll
    for (int j2 = 0; j2 < 7; j2++) {
        const int n = n0 + j2 * 16 + l15;
        #pragma unroll
        for (int i = 0; i < 2; i++) {
            #pragma unroll
            for (int r = 0; r < 4; r++) {
                const int m = wm + i * 16 + quad * 4 + r;
                __builtin_nontemporal_store(acc[i][j2][r] + bias_sm[m],
                                            &ob[(size_t)(m0 + m) * HW + n]);
            }
        }
    }
}

extern "C" void kernel_launch(void* const* d_in, const int* in_sizes, int n_in,
                              void* d_out, int out_size, void* d_ws, size_t ws_size,
                              hipStream_t stream) {
    (void)in_sizes; (void)n_in; (void)d_ws; (void)ws_size; (void)out_size;
    const float* x    = (const float*)d_in[0];
    const float* w    = (const float*)d_in[1];
    const float* bias = (const float*)d_in[2];
    float* out        = (float*)d_out;

    dim3 grid(64 * 4 * 7);   // 64 batches * 4 m-tiles * 7 n-tiles
    dim3 block(256);
    dynfc_kernel<<<grid, block, 0, stream>>>(x, w, bias, out);
}

// Round 4
// 262.214 us; speedup vs baseline: 1.1618x; 1.1618x over previous
//
#include <hip/hip_runtime.h>

// DynamicFC: out[b,o,h,w] = sum_i w[b,o,i] * x[b,i,h,w] + bias[b,o]
// Batched GEMM per b: M=Cout=512, N=HW=784, K=Cin=512, fp32 in/out.
// R6 vs R5 (R5 post-mortem: WAR race — single register set, load(t+2)
// clobbered tile t+1 before its LDS write -> absmax 65. The schedule needs
// TWO register sets, tile k -> set k&1):
//  - Dual register sets aA/bA, aB/bB, named vars (static indexing), schedule
//    as unrolled even/odd sub-iterations:
//      even: load setA<-tile t+2 | SB(0) | compute(t,buf0) | write setB->buf1 | bar
//      odd : load setB<-tile t+3 | SB(0) | compute(t,buf1) | write setA->buf0 | bar
//    Loads issued 2 tiles ahead, consumed end of NEXT sub-iter -> >=1 full
//    compute phase in flight even with __syncthreads' vmcnt(0) drain.
//  - sched_barrier(0) pins load issue above the MFMA block: RA must keep
//    both sets live (R3/R4 failure mode was the scheduler re-sinking loads).
//  - BK=32 so dual-set staging fits: ~170 VGPR; LDS dbuf 38.4 KB -> up to
//    3 blocks/CU (R4's 69 KB allowed only 2).
//  - B staging remapped (kg=tid>>5, ng=tid&31): each half-wave reads one
//    contiguous 448B row segment (was 8 scattered 128B segments).
//  - plain stores (NT streamed partial lines: WRITE 137 vs 103 MB ideal).

#define CIN  512
#define COUT 512
#define HW   784      // 28*28 = 7*112
#define BM   128
#define BN   112
#define BK   32
#define LSTR 40       // 32 + 8 pad bf16 (80B row)

typedef __bf16 bf16_t;
typedef __bf16 bf16x8 __attribute__((ext_vector_type(8)));
typedef __bf16 bf16x4 __attribute__((ext_vector_type(4)));
typedef float  f32x4  __attribute__((ext_vector_type(4)));

__device__ __forceinline__ bf16x8 pack8(f32x4 a, f32x4 b) {
    bf16x8 r;
    r[0] = (bf16_t)a[0]; r[1] = (bf16_t)a[1];
    r[2] = (bf16_t)a[2]; r[3] = (bf16_t)a[3];
    r[4] = (bf16_t)b[0]; r[5] = (bf16_t)b[1];
    r[6] = (bf16_t)b[2]; r[7] = (bf16_t)b[3];
    return r;
}

__global__ __launch_bounds__(256, 2) void dynfc_kernel(
    const float* __restrict__ x,     // [64][512][784]
    const float* __restrict__ w,     // [64][512][512]
    const float* __restrict__ bias,  // [64][512]
    float* __restrict__ out)         // [64][512][784]
{
    __shared__ bf16_t Asm[2][BM * LSTR];   // 2 x 10 KB
    __shared__ bf16_t Bsm[2][BN * LSTR];   // 2 x 8.75 KB  (total 38.4 KB)
    __shared__ float  bias_sm[BM];

    // XCD swizzle: whole batches per XCD so W+X re-reads hit that XCD's L2.
    const int bid   = blockIdx.x;        // 0..1791
    const int xcd   = bid & 7;
    const int j     = bid >> 3;          // 0..223
    const int batch = xcd + 8 * (j / 28);
    const int trem  = j % 28;            // 4 m-tiles * 7 n-tiles
    const int tm    = trem / 7;
    const int tn    = trem % 7;
    const int m0    = tm * BM;
    const int n0    = tn * BN;

    const int tid  = threadIdx.x;
    const int lane = tid & 63;
    const int wid  = tid >> 6;
    const int wm   = wid * 32;           // wave's 32-row slice
    const int l15  = lane & 15;
    const int quad = lane >> 4;

    const float* xb = x + (size_t)batch * CIN * HW;
    const float* wb = w + (size_t)batch * COUT * CIN;

    if (tid < 32) {
        f32x4 bv = *(const f32x4*)(bias + batch * COUT + m0 + tid * 4);
        *(f32x4*)&bias_sm[tid * 4] = bv;
    }

    // A staging: thread -> (row ar of 128, k-half ah of {0,16}); 16 fp32.
    const int ar = tid >> 1;
    const int ah = (tid & 1) * 16;
    // B staging: kg = tid>>5 (k-group of 4 rows), ng = tid&31 (col-group of 4).
    // Half-wave (ng 0..27 active) reads one contiguous 448B row segment.
    const int  kg      = tid >> 5;       // 0..7
    const int  ng      = tid & 31;       // 0..31
    const bool bactive = (ng < 28);      // 28*4 = 112 cols exactly

    const float* asrc = wb + (size_t)(m0 + ar) * CIN + ah;
    const float* bsrc = xb + (size_t)(kg * 4) * HW + n0 + ng * 4;

    f32x4 aA[4], bA[4], aB[4], bB[4];    // two staging register sets

#define LOAD_SET(aR, bR, t) do {                                              \
        const float* ap_ = asrc + (t) * BK;                                   \
        aR[0] = *(const f32x4*)(ap_);      aR[1] = *(const f32x4*)(ap_ + 4);  \
        aR[2] = *(const f32x4*)(ap_ + 8);  aR[3] = *(const f32x4*)(ap_ + 12); \
        if (bactive) {                                                        \
            const float* bp_ = bsrc + (size_t)((t) * BK) * HW;                \
            bR[0] = *(const f32x4*)(bp_);                                     \
            bR[1] = *(const f32x4*)(bp_ + HW);                                \
            bR[2] = *(const f32x4*)(bp_ + 2 * HW);                            \
            bR[3] = *(const f32x4*)(bp_ + 3 * HW);                            \
        }                                                                     \
    } while (0)

#define WRITE_SET(aR, bR, s) do {                                             \
        bf16_t* Ab_ = &Asm[s][0];                                             \
        bf16_t* Bb_ = &Bsm[s][0];                                             \
        *(bf16x8*)&Ab_[ar * LSTR + ah]     = pack8(aR[0], aR[1]);             \
        *(bf16x8*)&Ab_[ar * LSTR + ah + 8] = pack8(aR[2], aR[3]);             \
        if (bactive) {                                                        \
            _Pragma("unroll")                                                 \
            for (int nn = 0; nn < 4; nn++) {                                  \
                bf16x4 c_;                                                    \
                c_[0] = (bf16_t)bR[0][nn]; c_[1] = (bf16_t)bR[1][nn];         \
                c_[2] = (bf16_t)bR[2][nn]; c_[3] = (bf16_t)bR[3][nn];         \
                *(bf16x4*)&Bb_[(ng * 4 + nn) * LSTR + kg * 4] = c_;           \
            }                                                                 \
        }                                                                     \
    } while (0)

#define COMPUTE(s) do {                                                       \
        const bf16_t* Ab_ = &Asm[s][0];                                       \
        const bf16_t* Bb_ = &Bsm[s][0];                                       \
        bf16x8 af_[2], bf_[7];                                                \
        _Pragma("unroll")                                                     \
        for (int i = 0; i < 2; i++)                                           \
            af_[i] = *(const bf16x8*)&Ab_[(wm + i * 16 + l15) * LSTR + quad * 8]; \
        _Pragma("unroll")                                                     \
        for (int j2 = 0; j2 < 7; j2++)                                        \
            bf_[j2] = *(const bf16x8*)&Bb_[(j2 * 16 + l15) * LSTR + quad * 8];\
        __builtin_amdgcn_s_setprio(1);                                        \
        _Pragma("unroll")                                                     \
        for (int i = 0; i < 2; i++)                                           \
            _Pragma("unroll")                                                 \
            for (int j2 = 0; j2 < 7; j2++)                                    \
                acc[i][j2] = __builtin_amdgcn_mfma_f32_16x16x32_bf16(af_[i], bf_[j2], acc[i][j2], 0, 0, 0); \
        __builtin_amdgcn_s_setprio(0);                                        \
    } while (0)

    f32x4 acc[2][7] = {};

    // ---- prologue: tile0 -> buf0 (via setA); tile1 -> setB ----
    LOAD_SET(aA, bA, 0);
    WRITE_SET(aA, bA, 0);
    LOAD_SET(aB, bB, 1);
    __syncthreads();

    // tile k lives in buf[k&1] and register set (k&1 ? B : A)
    #pragma unroll
    for (int tt = 0; tt < 16; tt += 2) {
        // ---- even sub-iter: compute tile tt from buf0 ----
        if (tt + 2 < 16) LOAD_SET(aA, bA, tt + 2);   // setA freed last sub-iter
        __builtin_amdgcn_sched_barrier(0);           // pin loads above compute
        COMPUTE(0);
        WRITE_SET(aB, bB, 1);                        // tile tt+1 -> buf1
        __syncthreads();

        // ---- odd sub-iter: compute tile tt+1 from buf1 ----
        if (tt + 3 < 16) LOAD_SET(aB, bB, tt + 3);   // setB freed just above
        __builtin_amdgcn_sched_barrier(0);
        COMPUTE(1);
        if (tt + 2 < 16) WRITE_SET(aA, bA, 0);       // tile tt+2 -> buf0
        __syncthreads();
    }

#undef LOAD_SET
#undef WRITE_SET
#undef COMPUTE

    // ---- epilogue: add bias, plain store (7*112 == 784, no guard) ----
    // C/D layout: col = lane&15, row = quad*4 + r
    float* ob = out + (size_t)batch * COUT * HW;
    #pragma unroll
    for (int j2 = 0; j2 < 7; j2++) {
        const int n = n0 + j2 * 16 + l15;
        #pragma unroll
        for (int i = 0; i < 2; i++) {
            #pragma unroll
            for (int r = 0; r < 4; r++) {
                const int m = wm + i * 16 + quad * 4 + r;
                ob[(size_t)(m0 + m) * HW + n] = acc[i][j2][r] + bias_sm[m];
            }
        }
    }
}

extern "C" void kernel_launch(void* const* d_in, const int* in_sizes, int n_in,
                              void* d_out, int out_size, void* d_ws, size_t ws_size,
                              hipStream_t stream) {
    (void)in_sizes; (void)n_in; (void)d_ws; (void)ws_size; (void)out_size;
    const float* x    = (const float*)d_in[0];
    const float* w    = (const float*)d_in[1];
    const float* bias = (const float*)d_in[2];
    float* out        = (float*)d_out;

    dim3 grid(64 * 4 * 7);   // 64 batches * 4 m-tiles * 7 n-tiles
    dim3 block(256);
    dynfc_kernel<<<grid, block, 0, stream>>>(x, w, bias, out);
}